// Round 1
// baseline (9919.885 us; speedup 1.0000x reference)
//
#include <hip/hip_runtime.h>
#include <stdint.h>

typedef unsigned short u16;
typedef __attribute__((ext_vector_type(4))) float f32x4;
typedef __attribute__((ext_vector_type(8))) short bf16x8;

#define DEV __device__ __forceinline__

DEV u16 f2bf(float f) {
  union { float f; uint32_t u; } v; v.f = f;
  uint32_t r = (v.u + 0x7FFFu + ((v.u >> 16) & 1u)) >> 16;  // RNE
  return (u16)r;
}
DEV float bf2f(u16 h) {
  union { uint32_t u; float f; } v; v.u = ((uint32_t)h) << 16;
  return v.f;
}
DEV float sigmoidf(float x) { return 1.0f / (1.0f + expf(-x)); }

// async global->LDS, 16B per lane; lds base must be wave-uniform (HW adds lane*16)
DEV void gll16(const void* g, void* l) {
  __builtin_amdgcn_global_load_lds((__attribute__((address_space(1))) void*)g,
                                   (__attribute__((address_space(3))) void*)l,
                                   16, 0, 0);
}

// ---------------------------------------------------------------------------
// prep kernels
// ---------------------------------------------------------------------------
__global__ void convert_bf16_kernel(const float* __restrict__ in, u16* __restrict__ out, int n) {
  int i = (blockIdx.x * blockDim.x + threadIdx.x) * 4;
  if (i + 3 < n) {
    f32x4 v = *(const f32x4*)(in + i);
    uint64_t pk = (uint64_t)f2bf(v[0]) | ((uint64_t)f2bf(v[1]) << 16) |
                  ((uint64_t)f2bf(v[2]) << 32) | ((uint64_t)f2bf(v[3]) << 48);
    *(uint64_t*)(out + i) = pk;
  }
}

// out(C,R) bf16 = transpose(in(R,C) f32); R,C multiples of 32
__global__ __launch_bounds__(1024) void transpose_to_bf16(
    const float* __restrict__ in, u16* __restrict__ out, int R, int C) {
  __shared__ float tl[32][33];
  const int tx = threadIdx.x, ty = threadIdx.y;
  const int c0 = blockIdx.x * 32, r0 = blockIdx.y * 32;
  tl[ty][tx] = in[(size_t)(r0 + ty) * C + c0 + tx];
  __syncthreads();
  out[(size_t)(c0 + ty) * R + r0 + tx] = f2bf(tl[tx][ty]);
}

// ---------------------------------------------------------------------------
// GEMM: C(MxN) = A(MxK,bf16) @ Bt(NxK,bf16)^T   (m97 structure, 128x128, BK=64)
// mode 0: write Cf(f32) + Cb(bf16), no bias   (skip projection -> seq)
// mode 1: write Cb(bf16), +bias               (xg, bf16 storage)
// mode 2: write Cf(f32), +bias                (xg, f32 storage)
// ---------------------------------------------------------------------------
__global__ __launch_bounds__(256) void gemm_bt_kernel(
    const u16* __restrict__ A, const u16* __restrict__ Bt,
    const float* __restrict__ bias,
    float* __restrict__ Cf, u16* __restrict__ Cb,
    int M, int N, int K, int mode) {
  __shared__ u16 As[128 * 64];
  __shared__ u16 Bs[128 * 64];
  const int tid  = threadIdx.x;
  const int lane = tid & 63;
  const int wid  = tid >> 6;
  const int wr   = wid >> 1, wc = wid & 1;
  const size_t arow0 = (size_t)blockIdx.y * 128;
  const size_t brow0 = (size_t)blockIdx.x * 128;

  f32x4 acc[4][4];
#pragma unroll
  for (int m = 0; m < 4; ++m)
#pragma unroll
    for (int n = 0; n < 4; ++n) acc[m][n] = (f32x4){0.f, 0.f, 0.f, 0.f};

  for (int k0 = 0; k0 < K; k0 += 64) {
#pragma unroll
    for (int it = 0; it < 4; ++it) {
      const int slot = it * 4 + wid;         // wave-uniform
      const int ch   = slot * 64 + lane;     // 16B chunk id (0..1023)
      const int r    = ch >> 3;
      const int cc   = (ch & 7) * 8;
      gll16(A  + (arow0 + r) * K + k0 + cc, (void*)(As + slot * 64 * 8));
      gll16(Bt + (brow0 + r) * K + k0 + cc, (void*)(Bs + slot * 64 * 8));
    }
    __syncthreads();   // drains vmcnt (gll) too
#pragma unroll
    for (int kk = 0; kk < 2; ++kk) {
      const int ro = lane & 15;
      const int ko = kk * 32 + (lane >> 4) * 8;
      bf16x8 av[4], bv[4];
#pragma unroll
      for (int m = 0; m < 4; ++m) av[m] = *(const bf16x8*)(As + (wr * 64 + m * 16 + ro) * 64 + ko);
#pragma unroll
      for (int n = 0; n < 4; ++n) bv[n] = *(const bf16x8*)(Bs + (wc * 64 + n * 16 + ro) * 64 + ko);
#pragma unroll
      for (int m = 0; m < 4; ++m)
#pragma unroll
        for (int n = 0; n < 4; ++n)
          acc[m][n] = __builtin_amdgcn_mfma_f32_16x16x32_bf16(av[m], bv[n], acc[m][n], 0, 0, 0);
    }
    __syncthreads();
  }

  const int rb = (lane >> 4) * 4;
  const int cn = lane & 15;
#pragma unroll
  for (int m = 0; m < 4; ++m) {
#pragma unroll
    for (int n = 0; n < 4; ++n) {
      const size_t col = brow0 + wc * 64 + n * 16 + cn;
      const float badd = (mode != 0) ? bias[col] : 0.f;
#pragma unroll
      for (int r = 0; r < 4; ++r) {
        const size_t row = arow0 + wr * 64 + m * 16 + rb + r;
        const float v = acc[m][n][r] + badd;
        if (mode == 0) { Cf[row * N + col] = v; Cb[row * N + col] = f2bf(v); }
        else if (mode == 1) { Cb[row * N + col] = f2bf(v); }
        else { Cf[row * N + col] = v; }
      }
    }
  }
}

// ---------------------------------------------------------------------------
// One LSTM timestep: g = xg[:,t,:] + h_{t-1} @ Wr ; gates; c,h update.
// 64 WGs x 256 thr. WG owns 16 units (all 4 gates); wave w computes gate w.
// LDS-staged h (32x512) and WrT slice (64x512) per K-chunk, XOR-swizzled
// (row stride 1024B would be a 16-way bank conflict on ds_read_b128).
// ---------------------------------------------------------------------------
__global__ __launch_bounds__(256) void lstm_step_kernel(
    const u16* __restrict__ xgb, const float* __restrict__ xgf, int xg32,
    const u16* __restrict__ wrT,      // (4096,1024) bf16, layer slice
    u16* __restrict__ ys,             // (B*T, 1024) bf16; h_t stored at row b*256+t
    float* __restrict__ cst,          // (32,1024) f32 cell state
    float* __restrict__ hTf,          // (32,1024) f32 final h
    int t, int tLast) {
  __shared__ u16 Hs[32 * 512];
  __shared__ u16 Ws[64 * 512];
  __shared__ float gl[4][32][16];

  const int lane = threadIdx.x & 63;
  const int w    = threadIdx.x >> 6;     // gate id for compute
  const int u0   = blockIdx.x * 16;

  f32x4 acc0 = (f32x4){0.f, 0.f, 0.f, 0.f};
  f32x4 acc1 = acc0;

  if (t > 0) {
    for (int k0 = 0; k0 < 1024; k0 += 512) {
      if (k0) __syncthreads();  // protect restage
      // stage h_{t-1}: rows b=0..31, cols k0..k0+511 ; source-side swizzle
#pragma unroll
      for (int it = 0; it < 8; ++it) {
        const int slot = it * 4 + w;
        const int ch   = slot * 64 + lane;      // 0..2047
        const int r    = ch >> 6;               // batch row
        const int q    = (ch & 63) ^ (r & 7);   // swizzled 16B col chunk
        gll16(ys + ((size_t)(r * 256 + t - 1)) * 1024 + k0 + q * 8,
              (void*)(Hs + slot * 64 * 8));
      }
      // stage WrT rows {gate*1024 + u0 + j}, j=0..15, gates 0..3
#pragma unroll
      for (int it = 0; it < 16; ++it) {
        const int slot = it * 4 + w;
        const int ch   = slot * 64 + lane;      // 0..4095
        const int r    = ch >> 6;               // 0..63 = gate*16+j
        const int q    = (ch & 63) ^ (r & 7);
        const int gate = r >> 4, j = r & 15;
        gll16(wrT + ((size_t)(gate * 1024 + u0 + j)) * 1024 + k0 + q * 8,
              (void*)(Ws + slot * 64 * 8));
      }
      __syncthreads();
      const int r0 = lane & 15;
      const int hi = lane >> 4;
#pragma unroll
      for (int kk = 0; kk < 16; ++kk) {
        const int qb = kk * 4 + hi;
        const int sw = (qb ^ (r0 & 7)) * 8;     // un-swizzle on read
        bf16x8 a0 = *(const bf16x8*)(Hs + r0 * 512 + sw);
        bf16x8 a1 = *(const bf16x8*)(Hs + (16 + r0) * 512 + sw);
        bf16x8 b0 = *(const bf16x8*)(Ws + (w * 16 + r0) * 512 + sw);
        acc0 = __builtin_amdgcn_mfma_f32_16x16x32_bf16(a0, b0, acc0, 0, 0, 0);
        acc1 = __builtin_amdgcn_mfma_f32_16x16x32_bf16(a1, b0, acc1, 0, 0, 0);
      }
    }
  }

  // g -> LDS (D frag: col=lane&15, row=(lane>>4)*4+reg)
  {
    const int j  = lane & 15;
    const int rb = (lane >> 4) * 4;
    const size_t gcol = (size_t)w * 1024 + u0 + j;
#pragma unroll
    for (int m = 0; m < 2; ++m) {
      f32x4 a = m ? acc1 : acc0;
#pragma unroll
      for (int r = 0; r < 4; ++r) {
        const int b_ = m * 16 + rb + r;
        const size_t off = ((size_t)(b_ * 256 + t)) * 4096 + gcol;
        const float xv = xg32 ? xgf[off] : bf2f(xgb[off]);
        gl[w][b_][j] = a[r] + xv;
      }
    }
  }
  __syncthreads();

  for (int p = threadIdx.x; p < 512; p += 256) {
    const int b_ = p >> 4, j = p & 15;
    const int u  = u0 + j;
    const float i_ = sigmoidf(gl[0][b_][j]);
    const float f_ = sigmoidf(gl[1][b_][j]);
    const float cd = tanhf(gl[2][b_][j]);
    const float o_ = sigmoidf(gl[3][b_][j]);
    const float cold = (t == 0) ? 0.f : cst[b_ * 1024 + u];
    const float cn = f_ * cold + i_ * cd;
    cst[b_ * 1024 + u] = cn;
    const float h = o_ * tanhf(cn);
    ys[((size_t)(b_ * 256 + t)) * 1024 + u] = f2bf(h);
    if (t == tLast) hTf[b_ * 1024 + u] = h;
  }
}

// seq += ys (residual); refresh bf16 copy of seq
__global__ void seq_update_kernel(float* __restrict__ seqf, u16* __restrict__ seqb,
                                  const u16* __restrict__ ys, int n) {
  int i = (blockIdx.x * blockDim.x + threadIdx.x) * 4;
  if (i + 3 < n) {
    f32x4 s = *(f32x4*)(seqf + i);
    uint64_t yv = *(const uint64_t*)(ys + i);
    s[0] += bf2f((u16)(yv & 0xFFFF));
    s[1] += bf2f((u16)((yv >> 16) & 0xFFFF));
    s[2] += bf2f((u16)((yv >> 32) & 0xFFFF));
    s[3] += bf2f((u16)((yv >> 48) & 0xFFFF));
    *(f32x4*)(seqf + i) = s;
    uint64_t pk = (uint64_t)f2bf(s[0]) | ((uint64_t)f2bf(s[1]) << 16) |
                  ((uint64_t)f2bf(s[2]) << 32) | ((uint64_t)f2bf(s[3]) << 48);
    *(uint64_t*)(seqb + i) = pk;
  }
}

// out layout (2, L, B, U)
__global__ void finalize_kernel(const float* __restrict__ hTf, const float* __restrict__ cst,
                                float* __restrict__ out, int l) {
  const int idx = blockIdx.x * 256 + threadIdx.x;   // 0..32767 = b*1024+u
  out[(size_t)l * 32 * 1024 + idx]            = hTf[idx];
  out[(size_t)(4 + l) * 32 * 1024 + idx]      = cst[idx];
}

// ---------------------------------------------------------------------------
extern "C" void kernel_launch(void* const* d_in, const int* in_sizes, int n_in,
                              void* d_out, int out_size, void* d_ws, size_t ws_size,
                              hipStream_t stream) {
  const float* x     = (const float*)d_in[0];   // (32,256,512)
  const float* Wskip = (const float*)d_in[1];   // (512,1024)
  const float* Wk    = (const float*)d_in[2];   // (4,1024,4096)
  const float* Wr    = (const float*)d_in[3];   // (4,1024,4096)
  const float* bias  = (const float*)d_in[4];   // (4,4096)
  float* out = (float*)d_out;

  char* ws = (char*)d_ws;
  size_t o = 0;
  auto carve = [&](size_t bytes) -> char* {
    char* p = ws + o;
    o += (bytes + 255) & ~(size_t)255;
    return p;
  };
  u16*   xbf  = (u16*)  carve((size_t)8192 * 512 * 2);
  u16*   wskT = (u16*)  carve((size_t)1024 * 512 * 2);
  u16*   wkT  = (u16*)  carve((size_t)4 * 4096 * 1024 * 2);
  u16*   wrT  = (u16*)  carve((size_t)4 * 4096 * 1024 * 2);
  float* seqf = (float*)carve((size_t)8192 * 1024 * 4);
  u16*   seqb = (u16*)  carve((size_t)8192 * 1024 * 2);
  u16*   ysb  = (u16*)  carve((size_t)8192 * 1024 * 2);
  float* cbuf = (float*)carve((size_t)32 * 1024 * 4);
  float* hTf  = (float*)carve((size_t)32 * 1024 * 4);
  // xg: prefer f32 storage (accuracy) if workspace allows
  const int xg32 = (ws_size >= o + (size_t)8192 * 4096 * 4 + 512) ? 1 : 0;
  float* xgf = nullptr;
  u16*   xgb = nullptr;
  if (xg32) xgf = (float*)carve((size_t)8192 * 4096 * 4);
  else      xgb = (u16*)  carve((size_t)8192 * 4096 * 2);

  // ---- prep: bf16 conversions / weight transposes ----
  convert_bf16_kernel<<<4096, 256, 0, stream>>>(x, xbf, 8192 * 512);
  dim3 tb(32, 32);
  transpose_to_bf16<<<dim3(1024 / 32, 512 / 32), tb, 0, stream>>>(Wskip, wskT, 512, 1024);
  for (int l = 0; l < 4; ++l) {
    transpose_to_bf16<<<dim3(4096 / 32, 1024 / 32), tb, 0, stream>>>(
        Wk + (size_t)l * 1024 * 4096, wkT + (size_t)l * 4096 * 1024, 1024, 4096);
    transpose_to_bf16<<<dim3(4096 / 32, 1024 / 32), tb, 0, stream>>>(
        Wr + (size_t)l * 1024 * 4096, wrT + (size_t)l * 4096 * 1024, 1024, 4096);
  }

  // ---- skip projection: seq = x @ W_skip ----
  gemm_bt_kernel<<<dim3(1024 / 128, 8192 / 128), 256, 0, stream>>>(
      xbf, wskT, nullptr, seqf, seqb, 8192, 1024, 512, 0);

  // ---- layers ----
  for (int l = 0; l < 4; ++l) {
    gemm_bt_kernel<<<dim3(4096 / 128, 8192 / 128), 256, 0, stream>>>(
        seqb, wkT + (size_t)l * 4096 * 1024, bias + (size_t)l * 4096,
        xgf, xgb, 8192, 4096, 1024, xg32 ? 2 : 1);
    for (int t = 0; t < 256; ++t)
      lstm_step_kernel<<<64, 256, 0, stream>>>(xgb, xgf, xg32,
                                               wrT + (size_t)l * 4096 * 1024,
                                               ysb, cbuf, hTf, t, 255);
    finalize_kernel<<<128, 256, 0, stream>>>(hTf, cbuf, out, l);
    if (l < 3)
      seq_update_kernel<<<8192, 256, 0, stream>>>(seqf, seqb, ysb, 8192 * 1024);
  }
}